// Round 8
// baseline (159.664 us; speedup 1.0000x reference)
//
#include <hip/hip_runtime.h>

#define HID 50
#define TSTEPS 256
#define SPB 8               // samples per block -> grid 512 -> 2 blocks/CU
#define NW 4                // waves per block, 4 M-tiles each: 256 rows >= 200
#define THREADS (NW * 64)
#define HROW 72             // shorts per h-table row (144 B): quad stride 9 (mod 8 = 1)
#define XSTRIDE 260         // floats per sample row in x_lds (16B-aligned)

#if __has_builtin(__builtin_amdgcn_exp2f)
#define EXP2(x) __builtin_amdgcn_exp2f(x)
#else
#define EXP2(x) exp2f(x)
#endif
#define L2E 1.44269504088896340736f

typedef __attribute__((ext_vector_type(8))) _Float16 half8;
typedef __attribute__((ext_vector_type(4))) float f32x4;

static __device__ __forceinline__ f32x4 MF16(half8 a, half8 b, f32x4 c) {
    return __builtin_amdgcn_mfma_f32_16x16x32_f16(a, b, c, 0, 0, 0);
}
// 1/(1 + 2^a)
static __device__ __forceinline__ float sig2(float a) {
    return __builtin_amdgcn_rcpf(1.0f + EXP2(a));
}
static __device__ __forceinline__ float fast_tanh(float x) {
    return 1.0f - 2.0f * sig2(2.0f * L2E * x);
}

__global__ __launch_bounds__(THREADS, 2) void hybrid_lstm_4t(
    const float* __restrict__ x,      // [B,256,1]
    const float* __restrict__ W_ih,   // [200,1]
    const float* __restrict__ W_hh,   // [200,50]
    const float* __restrict__ b_ih,   // [200]
    const float* __restrict__ b_hh,   // [200]
    const float* __restrict__ Wp,     // [4,50]
    const float* __restrict__ bp,     // [4]
    const float* __restrict__ qw,     // [2,4,3]
    const float* __restrict__ Wo,     // [1,4]
    const float* __restrict__ bo,     // [1]
    float* __restrict__ out)          // [B,1]
{
    __shared__ __align__(16) float x_lds[SPB * XSTRIDE];
    // h table: [buf][row(sample 0..15)][slot(=unit) 0..63, pad..71] fp16.
    // Row stride 144 B -> bank-quad (s%8 + G + 4c) % 8: uniform -> conflict-free b128 reads.
    // Rows 8..15 stay zero (MFMA cols 8..15 unused).
    __shared__ __align__(16) _Float16 h_tab[2][16 * HROW];

    const int tid  = threadIdx.x;
    const int wid  = tid >> 6;        // 0..3
    const int lane = tid & 63;
    const int qs   = lane & 15;       // sample col / A-row-within-tile
    const int g2   = lane >> 4;       // K-group / C-row-group

    // ---------- prologue: zero h tables, stage x ----------
    {
        unsigned* hz = (unsigned*)&h_tab[0][0];
        for (int i = tid; i < 2 * 16 * HROW / 2; i += THREADS) hz[i] = 0u;
        const float* xg = x + (size_t)blockIdx.x * SPB * TSTEPS;
        for (int i = tid; i < SPB * TSTEPS; i += THREADS)
            x_lds[(i >> 8) * XSTRIDE + (i & 255)] = xg[i];
    }

    // ---------- A fragments: 4 tiles per wave, gate-scaled fp16, slot == unit ----------
    // tile T = 4*wid+ti: A-row qs -> unit uA = 4T + (qs>>2), gate q = qs&3 (i,f,g,o)
    // K element (kh,r): slot s = kh*32 + g2*8 + r = unit index (identity map)
    // gate scale: i,f,o rows * -log2e ; g row * 2*log2e (exp2-native gates)
    half8 Ah[4][2];
    {
        const int q    = qs & 3;
        const float sc = (q == 2) ? 2.0f * L2E : -L2E;
#pragma unroll
        for (int ti = 0; ti < 4; ++ti) {
            const int uA  = 4 * (4 * wid + ti) + (qs >> 2);
            const bool vr = (uA < HID);
            const int orow = q * HID + (vr ? uA : 0);
#pragma unroll
            for (int kh = 0; kh < 2; ++kh) {
#pragma unroll
                for (int r = 0; r < 8; ++r) {
                    const int s = kh * 32 + g2 * 8 + r;   // slot == unit
                    float v = 0.0f;
                    if (vr && s < HID) v = sc * W_hh[orow * HID + s];
                    Ah[ti][kh][r] = (_Float16)v;
                }
            }
        }
    }

    // acc-init consts per tile: acc_ti[reg] = gate 'reg' of unit 4*(4wid+ti)+g2
    // invalid units get 0 weights/bias -> h stays exactly 0 forever.
    float wihc[4][4], bsumc[4][4];
#pragma unroll
    for (int ti = 0; ti < 4; ++ti) {
        const int uC  = 4 * (4 * wid + ti) + g2;
        const bool cv = (uC < HID);
#pragma unroll
        for (int reg = 0; reg < 4; ++reg) {
            const float sc = (reg == 2) ? 2.0f * L2E : -L2E;
            const int orow = reg * HID + (cv ? uC : 0);
            wihc[ti][reg]  = cv ? sc * W_ih[orow] : 0.0f;
            bsumc[ti][reg] = cv ? sc * (b_ih[orow] + b_hh[orow]) : 0.0f;
        }
    }

    // post-repack cells: lane owns sample s_l, units uj = 16*wid + 8*hi8 + 4j + g2 (j=0,1)
    const int s_l  = qs & 7;
    const bool hi8 = (qs >= 8);
    const int u0w  = 16 * wid + (hi8 ? 8 : 0) + g2;
    const int u1w  = u0w + 4;
    _Float16* const wpA = &h_tab[0][s_l * HROW + u0w];
    _Float16* const wpB = &h_tab[0][s_l * HROW + u1w];

    __syncthreads();

    float cstA = 0.0f, cstB = 0.0f;
    half8 bh0, bh1;
    auto loadB = [&](int buf) {
        const _Float16* bp_ = &h_tab[buf][qs * HROW + g2 * 8];
        bh0 = *(const half8*)(bp_);
        bh1 = *(const half8*)(bp_ + 32);
    };

    loadB(1);   // h(-1) = 0 from zeroed buf1

    const float* xrow = &x_lds[s_l * XSTRIDE];

#pragma unroll 1
    for (int t4 = 0; t4 < TSTEPS; t4 += 4) {
        const float4 xq = *(const float4*)(xrow + t4);
#pragma unroll
        for (int k = 0; k < 4; ++k) {
            const float xt = (k == 0) ? xq.x : (k == 1) ? xq.y : (k == 2) ? xq.z : xq.w;
            // acc init = exact fp32 (scaled) bias + W_ih*x_t
            f32x4 a0, a1, a2, a3;
#pragma unroll
            for (int reg = 0; reg < 4; ++reg) {
                a0[reg] = fmaf(wihc[0][reg], xt, bsumc[0][reg]);
                a1[reg] = fmaf(wihc[1][reg], xt, bsumc[1][reg]);
                a2[reg] = fmaf(wihc[2][reg], xt, bsumc[2][reg]);
                a3[reg] = fmaf(wihc[3][reg], xt, bsumc[3][reg]);
            }
            a0 = MF16(Ah[0][0], bh0, a0);
            a1 = MF16(Ah[1][0], bh0, a1);
            a2 = MF16(Ah[2][0], bh0, a2);
            a3 = MF16(Ah[3][0], bh0, a3);
            a0 = MF16(Ah[0][1], bh1, a0);
            a1 = MF16(Ah[1][1], bh1, a1);
            a2 = MF16(Ah[2][1], bh1, a2);
            a3 = MF16(Ah[3][1], bh1, a3);

            // repack: lanes qs>=8 take tiles 2,3 from lane qs-8 -> 2 cells/lane, all packed
            f32x4 cA, cB;
#pragma unroll
            for (int reg = 0; reg < 4; ++reg) {
                const float r2 = __shfl_xor(a2[reg], 8);
                const float r3 = __shfl_xor(a3[reg], 8);
                cA[reg] = hi8 ? r2 : a0[reg];
                cB[reg] = hi8 ? r3 : a1[reg];
            }

            // gates, cell A (unit u0w)
            const float iA = sig2(cA[0]);
            const float fA = sig2(cA[1]);
            const float gA = 1.0f - 2.0f * sig2(cA[2]);
            const float oA = sig2(cA[3]);
            cstA = fmaf(fA, cstA, iA * gA);
            const float hA = oA * fast_tanh(cstA);
            // gates, cell B (unit u1w)
            const float iB = sig2(cB[0]);
            const float fB = sig2(cB[1]);
            const float gB = 1.0f - 2.0f * sig2(cB[2]);
            const float oB = sig2(cB[3]);
            cstB = fmaf(fB, cstB, iB * gB);
            const float hB = oB * fast_tanh(cstB);

            const int boff = (k & 1) * (16 * HROW);   // static per unrolled k
            wpA[boff] = (_Float16)hA;
            wpB[boff] = (_Float16)hB;
            __syncthreads();
            loadB(k & 1);                             // h(t) for next step
        }
    }

    // ---------- epilogue: angles + 4-qubit circuit, 4 samples per wave (waves 0-1) ----------
    if (wid < 2) {
        const int sm  = 4 * wid + (lane >> 4);   // 0..7
        const int ql  = lane & 15;
        const int grp = lane & 48;

        const _Float16* t1 = &h_tab[1][0];       // h(255) lives in buf1
        float ang0 = bp[0], ang1 = bp[1], ang2 = bp[2], ang3 = bp[3];
#pragma unroll
        for (int kk = 0; kk < HID; ++kk) {
            const float hk = (float)t1[sm * HROW + kk];   // slot == unit
            ang0 = fmaf(Wp[0 * HID + kk], hk, ang0);
            ang1 = fmaf(Wp[1 * HID + kk], hk, ang1);
            ang2 = fmaf(Wp[2 * HID + kk], hk, ang2);
            ang3 = fmaf(Wp[3 * HID + kk], hk, ang3);
        }
        float ang[4];
        ang[0] = fast_tanh(ang0) * 1.57079632679489662f;
        ang[1] = fast_tanh(ang1) * 1.57079632679489662f;
        ang[2] = fast_tanh(ang2) * 1.57079632679489662f;
        ang[3] = fast_tanh(ang3) * 1.57079632679489662f;

        float ar = (ql == 0) ? 1.0f : 0.0f;
        float ai = 0.0f;

        // RX embedding
#pragma unroll
        for (int wq = 0; wq < 4; ++wq) {
            const int mask = 8 >> wq;
            float s_, c_;
            __sincosf(0.5f * ang[wq], &s_, &c_);
            const float pr = __shfl_xor(ar, mask);
            const float pi = __shfl_xor(ai, mask);
            const float nr = c_ * ar + s_ * pi;
            const float ni = c_ * ai - s_ * pr;
            ar = nr; ai = ni;
        }
        // StronglyEntanglingLayers
#pragma unroll
        for (int l = 0; l < 2; ++l) {
#pragma unroll
            for (int wq = 0; wq < 4; ++wq) {
                const float phi = qw[(l * 4 + wq) * 3 + 0];
                const float th  = qw[(l * 4 + wq) * 3 + 1];
                const float om  = qw[(l * 4 + wq) * 3 + 2];
                float st_, ct_, sa, ca, sb, cb;
                __sincosf(0.5f * th, &st_, &ct_);
                __sincosf(0.5f * (phi + om), &sa, &ca);
                __sincosf(0.5f * (phi - om), &sb, &cb);
                const int mask = 8 >> wq;
                const bool bit = (ql & mask) != 0;
                const float dr  = ca * ct_;
                const float di  = (bit ? sa : -sa) * ct_;
                const float orr = (bit ? cb : -cb) * st_;
                const float oi  = -sb * st_;
                const float pr = __shfl_xor(ar, mask);
                const float pi = __shfl_xor(ai, mask);
                const float nr = dr * ar - di * ai + orr * pr - oi * pi;
                const float ni = dr * ai + di * ar + orr * pi + oi * pr;
                ar = nr; ai = ni;
            }
            const int r = (l % 3) + 1;
#pragma unroll
            for (int wq = 0; wq < 4; ++wq) {
                const int mc  = 8 >> wq;
                const int mt  = 8 >> ((wq + r) % 4);
                const int src = (ql & mc) ? (ql ^ mt) : ql;
                ar = __shfl(ar, grp | src);
                ai = __shfl(ai, grp | src);
            }
        }
        const float prob = ar * ar + ai * ai;
        float coeff = 0.0f;
#pragma unroll
        for (int wq = 0; wq < 4; ++wq) {
            const float sgn = (ql & (8 >> wq)) ? -1.0f : 1.0f;
            coeff = fmaf(sgn, Wo[wq], coeff);
        }
        float v = prob * coeff;
        v += __shfl_xor(v, 1);
        v += __shfl_xor(v, 2);
        v += __shfl_xor(v, 4);
        v += __shfl_xor(v, 8);
        if (ql == 0) out[blockIdx.x * SPB + sm] = v + bo[0];
    }
}

extern "C" void kernel_launch(void* const* d_in, const int* in_sizes, int n_in,
                              void* d_out, int out_size, void* d_ws, size_t ws_size,
                              hipStream_t stream) {
    const float* x    = (const float*)d_in[0];
    const float* W_ih = (const float*)d_in[1];
    const float* W_hh = (const float*)d_in[2];
    const float* b_ih = (const float*)d_in[3];
    const float* b_hh = (const float*)d_in[4];
    const float* Wp   = (const float*)d_in[5];
    const float* bp   = (const float*)d_in[6];
    const float* qw   = (const float*)d_in[7];
    const float* Wo   = (const float*)d_in[8];
    const float* bo   = (const float*)d_in[9];
    float* out = (float*)d_out;

    const int B = in_sizes[0] / TSTEPS;
    hybrid_lstm_4t<<<B / SPB, THREADS, 0, stream>>>(x, W_ih, W_hh, b_ih, b_hh,
                                                    Wp, bp, qw, Wo, bo, out);
}